// Round 3
// baseline (11297.171 us; speedup 1.0000x reference)
//
#include <hip/hip_runtime.h>

// Problem constants
#define BB 16
#define TT 4096
#define DD 256     // DIM
#define HH 128     // hidden
#define G3 384     // 3*H
#define MM (BB*TT) // 65536 rows

// ---------------- Input-projection GEMM (fp32) ----------------
// XG[dir][m][0:384] = X[m][0:256] @ Wi[dir][0:256][0:384]
// Tiles: BM=128, BN=128, BK=16; 256 threads; 8x8 per thread.
#define Bb 128
#define Bn 128
#define Bk 16

__global__ __launch_bounds__(256) void gemm_in(const float* __restrict__ X,
                                               const float* __restrict__ Wi,
                                               float* __restrict__ XG) {
    __shared__ __align__(16) float As[Bk][Bb + 4];   // [k][m]
    __shared__ __align__(16) float Bs[Bk][Bn + 4];   // [k][n]
    const int tid = threadIdx.x;
    const int m0  = blockIdx.y * Bb;
    const int nb  = blockIdx.x;              // 0..5 over N=768 (two dirs x 384)
    const int n0  = nb * Bn;
    const int dir = (n0 >= G3) ? 1 : 0;
    const int nloc0 = n0 - dir * G3;         // 0, 128, or 256
    const float* Wd = Wi + (size_t)dir * DD * G3;

    const int tx = tid & 15;
    const int ty = tid >> 4;
    float acc[8][8];
    #pragma unroll
    for (int i = 0; i < 8; ++i)
        #pragma unroll
        for (int j = 0; j < 8; ++j) acc[i][j] = 0.f;

    for (int k0 = 0; k0 < DD; k0 += Bk) {
        // Stage A: 128 rows x 16 k (512 float4, 2 per thread), transposed As[k][m]
        #pragma unroll
        for (int p = 0; p < 2; ++p) {
            int idx = tid + p * 256;         // 0..511
            int row = idx >> 2;              // 0..127
            int c4  = (idx & 3) * 4;         // 0,4,8,12
            float4 v = *(const float4*)(X + (size_t)(m0 + row) * DD + k0 + c4);
            As[c4 + 0][row] = v.x;
            As[c4 + 1][row] = v.y;
            As[c4 + 2][row] = v.z;
            As[c4 + 3][row] = v.w;
        }
        // Stage B: 16 k-rows x 128 cols (512 float4, 2 per thread)
        #pragma unroll
        for (int p = 0; p < 2; ++p) {
            int idx  = tid + p * 256;        // 0..511
            int krow = idx >> 5;             // 0..15
            int c4   = (idx & 31) * 4;       // 0..124
            float4 v = *(const float4*)(Wd + (size_t)(k0 + krow) * G3 + nloc0 + c4);
            *(float4*)(&Bs[krow][c4]) = v;
        }
        __syncthreads();
        #pragma unroll
        for (int k = 0; k < Bk; ++k) {
            float4 a0 = *(const float4*)(&As[k][ty * 8]);
            float4 a1 = *(const float4*)(&As[k][ty * 8 + 4]);
            float4 b0 = *(const float4*)(&Bs[k][tx * 8]);
            float4 b1 = *(const float4*)(&Bs[k][tx * 8 + 4]);
            float av[8] = {a0.x, a0.y, a0.z, a0.w, a1.x, a1.y, a1.z, a1.w};
            float bv[8] = {b0.x, b0.y, b0.z, b0.w, b1.x, b1.y, b1.z, b1.w};
            #pragma unroll
            for (int i = 0; i < 8; ++i)
                #pragma unroll
                for (int j = 0; j < 8; ++j) acc[i][j] += av[i] * bv[j];
        }
        __syncthreads();
    }
    // Epilogue
    #pragma unroll
    for (int i = 0; i < 8; ++i) {
        int m = m0 + ty * 8 + i;
        float* dst = XG + ((size_t)dir * MM + m) * G3 + nloc0 + tx * 8;
        *(float4*)dst       = make_float4(acc[i][0], acc[i][1], acc[i][2], acc[i][3]);
        *(float4*)(dst + 4) = make_float4(acc[i][4], acc[i][5], acc[i][6], acc[i][7]);
    }
}

// ---------------- Recurrence ----------------
__device__ __forceinline__ float fast_sigmoid(float x) {
    float e = __expf(-x);
    return __builtin_amdgcn_rcpf(1.f + e);
}
__device__ __forceinline__ float fast_tanh(float x) {
    float e = __expf(2.f * x);
    return 1.f - 2.f * __builtin_amdgcn_rcpf(1.f + e);
}

// grid = 32 (dir,batch); block = 384 (one thread per packed gate column)
__global__ __launch_bounds__(384, 2) void gru_rec(const float* __restrict__ XG,
                                                  const float* __restrict__ Wh,
                                                  const float* __restrict__ bh,
                                                  float* __restrict__ Xout) {
    const int wg  = blockIdx.x;     // 0..31
    const int dir = wg & 1;
    const int b   = wg >> 1;
    const int j   = threadIdx.x;    // 0..383

    const float* W = Wh + (size_t)dir * HH * G3;
    const float bias = bh[dir * G3 + j];

    __shared__ __align__(16) float hs[HH];
    __shared__ float rs[HH], zs[HH], ms[HH], xns[HH];

    float w[HH];
    #pragma unroll
    for (int k = 0; k < HH; ++k) w[k] = W[(size_t)k * G3 + j];

    if (j < HH) hs[j] = 0.f;
    __syncthreads();

    const float* xg = XG + ((size_t)dir * MM + (size_t)b * TT) * G3;
    float* outp = Xout + (size_t)b * TT * DD + dir * HH;

    int row0 = dir ? (TT - 1) : 0;
    float xv = xg[(size_t)row0 * G3 + j];   // prefetch t=0

    const float4* h4 = (const float4*)hs;

    for (int t = 0; t < TT; ++t) {
        const int tt = dir ? (TT - 1 - t) : t;
        const int tn = dir ? (TT - 2 - t) : (t + 1);
        float xv_next = 0.f;
        if (t + 1 < TT) xv_next = xg[(size_t)tn * G3 + j];

        float a0 = 0.f, a1 = 0.f, a2 = 0.f, a3 = 0.f;
        #pragma unroll
        for (int k = 0; k < HH; k += 4) {
            float4 hv = h4[k >> 2];
            a0 += hv.x * w[k + 0];
            a1 += hv.y * w[k + 1];
            a2 += hv.z * w[k + 2];
            a3 += hv.w * w[k + 3];
        }
        float acc = (a0 + a1) + (a2 + a3) + bias;

        if (j < HH) {
            rs[j] = fast_sigmoid(xv + acc);
        } else if (j < 2 * HH) {
            zs[j - HH] = fast_sigmoid(xv + acc);
        } else {
            ms[j - 2 * HH]  = acc;   // h@Whn + bhn (gated by r per flax GRUCell)
            xns[j - 2 * HH] = xv;
        }
        __syncthreads();

        if (j < HH) {
            float n  = fast_tanh(xns[j] + rs[j] * ms[j]);
            float z  = zs[j];
            float hn = (1.f - z) * n + z * hs[j];
            hs[j] = hn;
            outp[(size_t)tt * DD + j] = hn;
        }
        xv = xv_next;
        __syncthreads();
    }
}

// ---------------- Launch ----------------
// ws usage: XG only = 2*65536*384*4 = 201.3 MB (round-1's 335 MB overflowed ws
// and faulted; round-2 proved ~224 MiB is safe). Inter-layer activations
// ping-pong through d_out itself: layer l's recurrence fully rewrites d_out,
// layer l+1's GEMM consumes it before the next rewrite. Stream-ordered, and
// every call recomputes d_out from d_in alone (no cross-call state).
extern "C" void kernel_launch(void* const* d_in, const int* in_sizes, int n_in,
                              void* d_out, int out_size, void* d_ws, size_t ws_size,
                              hipStream_t stream) {
    const float* x  = (const float*)d_in[0];   // [16,4096,256]
    const float* Wi = (const float*)d_in[1];   // [3,2,256,384]
    const float* Wh = (const float*)d_in[2];   // [3,2,128,384]
    const float* bh = (const float*)d_in[3];   // [3,2,384]
    float* out = (float*)d_out;                // [16,4096,256]

    float* XG = (float*)d_ws;                  // [2, 65536, 384] fp32

    for (int l = 0; l < 3; ++l) {
        const float* in = (l == 0) ? x : out;
        const float* Wil = Wi + (size_t)l * 2 * DD * G3;
        const float* Whl = Wh + (size_t)l * 2 * HH * G3;
        const float* bhl = bh + (size_t)l * 2 * G3;

        gemm_in<<<dim3(6, MM / Bb), 256, 0, stream>>>(in, Wil, XG);
        gru_rec<<<32, 384, 0, stream>>>(XG, Whl, bhl, out);
    }
}